// Round 4
// baseline (993.351 us; speedup 1.0000x reference)
//
#include <hip/hip_runtime.h>

#define BATCH 1024
#define SEQ   1024
#define FDIM  36
#define HID   20
#define G3    60
#define CR    64          // rows per LDS gi chunk
#define NCHUNK (SEQ/CR)   // 16

typedef float v2f __attribute__((ext_vector_type(2)));

__device__ __forceinline__ float fast_sigmoid(float x){
    return __builtin_amdgcn_rcpf(1.0f + __expf(-x));
}
__device__ __forceinline__ float fast_tanh(float x){
    return fmaf(-2.0f, __builtin_amdgcn_rcpf(1.0f + __expf(2.0f*x)), 1.0f);
}

// One block per batch element, 2 waves:
//  wave0 (consumer): encoder GRU then decoder GRU (R3-proven gate-row-major form)
//  wave1 (producer): embed/concat -> origin rows + gi = Wih1@x+bih1 into a
//                    double-buffered LDS chunk (64 steps). __syncthreads pipelines.
// gi never touches HBM. Producer has ~3x slack vs consumer.
//
// Ledger of measured lessons:
//  R8: permlane gate relayout (2 dots/lane, no bpermute) = +143cy/step LOSS.
//      -> extra wave64 issue outweighs bpermute latency. Keep single-dot form.
//  R9: store-drain unroll + dsh pre-issue = NEUTRAL. Store latency was hidden.
//  R7-R8 subtraction: 36-readlane x-broadcast cost ~940cy/step vs LDS broadcast
//      -> v_readlane->SGPR->VALU consumer pairs serialize (~26cy each).
//  R10 (this round): the per-step 20x READLANE h-broadcast is the same poison
//      pattern (~500cy/step, every one of 2047 steps). Replace with LDS
//      broadcast: 1 unconditional ds_write of h + 5 broadcast ds_read_b128.
//      Values and FMA order unchanged -> bit-identical output.
//      Also: z = shfl(sigmoid(v)) instead of sigmoid(shfl(v)) -- one fewer
//      transcendental per gate step, z-bpermute hides under the n-tanh.
//
// Register discipline (R6 lesson): decoder weights are loaded AFTER the chunk
// loop (live range must not span it). __launch_bounds__(128,2): 256-VGPR cap.
__global__ __launch_bounds__(128, 2)
void gru_fused(const float* __restrict__ x,
               const int* __restrict__ oh,
               const float* __restrict__ e0, const float* __restrict__ e1,
               const float* __restrict__ e2, const float* __restrict__ e3,
               const float* __restrict__ Wih1g, const float* __restrict__ Whh1g,
               const float* __restrict__ bih1g, const float* __restrict__ bhh1g,
               const float* __restrict__ Wih2g, const float* __restrict__ Whh2g,
               const float* __restrict__ bih2g, const float* __restrict__ bhh2g,
               const float* __restrict__ Wfcg,  const float* __restrict__ bfcg,
               float* __restrict__ origin, float* __restrict__ out2)
{
    __shared__ __align__(16) float gbuf[2][CR][G3];  // 30 KB gi double buffer
    __shared__ __align__(16) float psh[64];          // producer broadcast scratch
    __shared__ __align__(16) float dsh[64];          // decoder x broadcast
    __shared__ __align__(16) float hsh[64];          // h broadcast (consumer only)

    const int lane   = threadIdx.x & 63;
    const bool is_enc = (threadIdx.x < 64);          // wave0 = consumer
    const int b = __builtin_amdgcn_readfirstlane(blockIdx.x);

    const int k = lane < G3 ? lane : G3 - 1;

    // ---- consumer cross-loop state (kept minimal: whh1 + hs only) ----
    float whh1[HID];
    float bh1 = 0.f;
    float hs[HID];
    float hv = 0.0f;
    if (is_enc) {
        #pragma unroll
        for (int u = 0; u < HID; u++) whh1[u] = Whh1g[k * HID + u];
        bh1 = bhh1g[k];
        #pragma unroll
        for (int u = 0; u < HID; u++) hs[u] = 0.0f;
    }

    // ---- producer state ----
    const int j = lane;
    const float* tbl; int ohc, eshift, sub;
    if (j < 16)      { tbl = e0; ohc = 0; eshift = 2; sub = j - 12; }
    else if (j < 20) { tbl = e1; ohc = 1; eshift = 2; sub = j - 16; }
    else if (j < 28) { tbl = e2; ohc = 2; eshift = 3; sub = j - 20; }
    else             { tbl = e3; ohc = 3; eshift = 3; sub = j - 28; }
    if (sub < 0) sub = 0;
    if (sub > 7) sub = 7;
    const bool from_x = (j < 12);
    const float* pa = from_x ? (x + j) : (tbl + sub);
    v2f w1p[FDIM/2]; float bi1 = 0.f;
    if (!is_enc) {
        #pragma unroll
        for (int q = 0; q < FDIM/2; q++) w1p[q] = ((const v2f*)(Wih1g + k * FDIM))[q];
        bi1 = bih1g[k];
    }

// h broadcast via LDS (R10): unconditional write (lanes >=20 write junk that is
// never read), then 5 broadcast float4 reads -> hs in VGPRs. Same-wave DS
// ordering guarantees read-after-write without a barrier.
#define HS_BCAST(HVAL) do {                                                  \
        hsh[lane] = (HVAL);                                                  \
        const float4* hq_ = (const float4*)hsh;                              \
        float4 t0_ = hq_[0], t1_ = hq_[1], t2_ = hq_[2], t3_ = hq_[3],       \
               t4_ = hq_[4];                                                 \
        hs[0]=t0_.x;  hs[1]=t0_.y;  hs[2]=t0_.z;  hs[3]=t0_.w;               \
        hs[4]=t1_.x;  hs[5]=t1_.y;  hs[6]=t1_.z;  hs[7]=t1_.w;               \
        hs[8]=t2_.x;  hs[9]=t2_.y;  hs[10]=t2_.z; hs[11]=t2_.w;              \
        hs[12]=t3_.x; hs[13]=t3_.y; hs[14]=t3_.z; hs[15]=t3_.w;              \
        hs[16]=t4_.x; hs[17]=t4_.y; hs[18]=t4_.z; hs[19]=t4_.w;              \
    } while (0)

#define GATE_STEP(GIV, WHH, BH, HVAR) do {                                   \
        float h0 = BH, h1 = 0.f, h2 = 0.f, h3 = 0.f;                         \
        _Pragma("unroll")                                                    \
        for (int uu = 0; uu < HID; uu += 4) {                                \
            h0 = fmaf(WHH[uu + 0], hs[uu + 0], h0);                          \
            h1 = fmaf(WHH[uu + 1], hs[uu + 1], h1);                          \
            h2 = fmaf(WHH[uu + 2], hs[uu + 2], h2);                          \
            h3 = fmaf(WHH[uu + 3], hs[uu + 3], h3);                          \
        }                                                                    \
        float gh = (h0 + h1) + (h2 + h3);                                    \
        float v   = (GIV) + gh;                                              \
        float in_ = __shfl((GIV),(lane + 40) & 63);                          \
        float hn  = __shfl(gh,   (lane + 40) & 63);                          \
        float s = fast_sigmoid(v);       /* r on own lane */                 \
        float z = __shfl(s, (lane + 20) & 63); /* shfl(sig(v)) == sig(shfl(v)) */ \
        float n = fast_tanh(fmaf(s, hn, in_));                               \
        HVAR = n + z * (HVAR - n);                                           \
        HS_BCAST(HVAR);                                                      \
    } while (0)

#define CONSUME_CHUNK(CB) do {                                               \
        const float* gp = &gbuf[CB][0][k];                                   \
        float ga = gp[0], gbv = gp[G3];                                      \
        _Pragma("unroll 1")                                                  \
        for (int i = 0; i < CR; i += 2) {                                    \
            float ge = ga, go = gbv;                                         \
            if (i < CR - 2) ga = gp[(i + 2) * G3];                           \
            GATE_STEP(ge, whh1, bh1, hv);                                    \
            if (i < CR - 2) gbv = gp[(i + 3) * G3];                          \
            GATE_STEP(go, whh1, bh1, hv);                                    \
        }                                                                    \
    } while (0)

    // ---------------- pipelined chunk loop ----------------
    #pragma unroll 1
    for (int c = 0; c < NCHUNK; ++c) {
        if (!is_enc) {
            const int rbase = b * SEQ + c * CR;
            float* gdst = &gbuf[c & 1][0][0];
            const float4* xp4 = (const float4*)psh;
            #pragma unroll 1
            for (int g = 0; g < CR / 8; ++g) {
                int ohv[8];
                #pragma unroll
                for (int n = 0; n < 8; n++)
                    ohv[n] = oh[(rbase + 8 * g + n) * 4 + ohc];
                float valv[8];
                #pragma unroll
                for (int n = 0; n < 8; n++) {
                    int R = rbase + 8 * g + n;
                    int off = from_x ? (R * 12) : (ohv[n] << eshift);
                    valv[n] = pa[off];
                }
                #pragma unroll
                for (int n = 0; n < 8; n++) {
                    const int i = 8 * g + n;
                    const size_t R = (size_t)(rbase + i);
                    psh[lane] = valv[n];              // same-wave DS ordering
                    if (lane < FDIM) origin[R * FDIM + lane] = valv[n];
                    v2f a0 = {bi1, 0.f}, a1 = {0.f, 0.f};
                    #pragma unroll
                    for (int q = 0; q < 9; q++) {
                        float4 xv4 = xp4[q];
                        v2f xlo = {xv4.x, xv4.y}, xhi = {xv4.z, xv4.w};
                        a0 = __builtin_elementwise_fma(w1p[2*q],     xlo, a0);
                        a1 = __builtin_elementwise_fma(w1p[2*q + 1], xhi, a1);
                    }
                    float gg = (a0.x + a1.x) + (a0.y + a1.y);
                    if (lane < G3) gdst[i * G3 + lane] = gg;
                }
            }
        } else if (c > 0) {
            CONSUME_CHUNK((c - 1) & 1);
        }
        __syncthreads();
    }
    if (!is_enc) return;              // producer done (after its final barrier)

    CONSUME_CHUNK((NCHUNK - 1) & 1);  // last chunk; no further barriers

    // ---- decoder weights loaded only now (live range does not span chunk loop) ----
    const int kf = lane < FDIM ? lane : FDIM - 1;
    float whh2[HID], wfc[HID];
    v2f wih2p[FDIM/2];
    #pragma unroll
    for (int q = 0; q < FDIM/2; q++) wih2p[q] = ((const v2f*)(Wih2g + k * FDIM))[q];
    #pragma unroll
    for (int u = 0; u < HID; u++) whh2[u] = Whh2g[k * HID + u];
    #pragma unroll
    for (int u = 0; u < HID; u++) wfc[u] = Wfcg[kf * HID + u];
    const float bi2 = bih2g[k], bh2 = bhh2g[k];
    const float bf  = bfcg[kf];

    // ---------------- handoff ----------------
    float hvd = fast_tanh(hv);
    HS_BCAST(hvd);

    float* orow = out2 + ((size_t)b * SEQ + (SEQ - 1)) * FDIM;
    const v2f* xp = (const v2f*)dsh;

    float xv0;
    {
        float f0 = bf, f1 = 0.f, f2 = 0.f, f3 = 0.f;
        #pragma unroll
        for (int u = 0; u < HID; u += 4) {
            f0 = fmaf(wfc[u + 0], hs[u + 0], f0);
            f1 = fmaf(wfc[u + 1], hs[u + 1], f1);
            f2 = fmaf(wfc[u + 2], hs[u + 2], f2);
            f3 = fmaf(wfc[u + 3], hs[u + 3], f3);
        }
        xv0 = fast_tanh((f0 + f1) + (f2 + f3));
    }
    dsh[lane] = xv0;                  // intra-wave broadcast (same wave)
    // pre-issue step-1 x reads (same-wave DS ordering: safe, no barrier)
    v2f xsA[FDIM/2], xsB[FDIM/2];
    #pragma unroll
    for (int q = 0; q < FDIM/2; q++) xsA[q] = xp[q];
    if (lane < FDIM) orow[lane] = xv0;

// One decoder step. XSIN: pre-loaded x regs for this step. XSOUT: regs to
// pre-issue next step's dsh reads into. XST: store register (alternates A/B).
// h broadcast via HS_BCAST (R10); z via shfl-after-sigmoid.
#define DEC_STEP(XSIN, XSOUT, XST) do {                                      \
        float h0 = bh2, h1 = 0.f, h2 = 0.f, h3 = 0.f;                        \
        _Pragma("unroll")                                                    \
        for (int u = 0; u < HID; u += 4) {                                   \
            h0 = fmaf(whh2[u + 0], hs[u + 0], h0);                           \
            h1 = fmaf(whh2[u + 1], hs[u + 1], h1);                           \
            h2 = fmaf(whh2[u + 2], hs[u + 2], h2);                           \
            h3 = fmaf(whh2[u + 3], hs[u + 3], h3);                           \
        }                                                                    \
        float gh = (h0 + h1) + (h2 + h3);                                    \
        v2f accA = {bi2, 0.f}, accB = {0.f, 0.f};                            \
        _Pragma("unroll")                                                    \
        for (int q = 0; q < FDIM/2; q += 2) {                                \
            accA = __builtin_elementwise_fma(wih2p[q],     XSIN[q],     accA); \
            accB = __builtin_elementwise_fma(wih2p[q + 1], XSIN[q + 1], accB); \
        }                                                                    \
        float gi = (accA.x + accB.x) + (accA.y + accB.y);                    \
        float v   = gi + gh;                                                 \
        float in_ = __shfl(gi, (lane + 40) & 63);                            \
        float hn  = __shfl(gh, (lane + 40) & 63);                            \
        float s = fast_sigmoid(v);                                           \
        float z = __shfl(s, (lane + 20) & 63);                               \
        float n = fast_tanh(fmaf(s, hn, in_));                               \
        float hraw = n + z * (hvd - n);                                      \
        hvd = fast_tanh(hraw);                                               \
        HS_BCAST(hvd);                                                       \
        float f0 = bf, f1 = 0.f, f2 = 0.f, f3 = 0.f;                         \
        _Pragma("unroll")                                                    \
        for (int u = 0; u < HID; u += 4) {                                   \
            f0 = fmaf(wfc[u + 0], hs[u + 0], f0);                            \
            f1 = fmaf(wfc[u + 1], hs[u + 1], f1);                            \
            f2 = fmaf(wfc[u + 2], hs[u + 2], f2);                            \
            f3 = fmaf(wfc[u + 3], hs[u + 3], f3);                            \
        }                                                                    \
        XST = fast_tanh((f0 + f1) + (f2 + f3));                              \
        orow -= FDIM;                                                        \
        dsh[lane] = XST;              /* write x, then immediately ... */    \
        _Pragma("unroll")                                                    \
        for (int q = 0; q < FDIM/2; q++) XSOUT[q] = xp[q]; /* pre-issue */   \
        if (lane < FDIM) orow[lane] = XST;                                   \
    } while (0)

    // ---------------- decoder: 511 unrolled pairs + 1 peeled = 1023 steps ----
    float xvA, xvB;
    #pragma unroll 1
    for (int i = 0; i < (SEQ - 2) / 2; ++i) {
        DEC_STEP(xsA, xsB, xvA);
        DEC_STEP(xsB, xsA, xvB);
    }
    DEC_STEP(xsA, xsB, xvA);          // final step (its XSOUT pre-issue is dead, harmless)
}

extern "C" void kernel_launch(void* const* d_in, const int* in_sizes, int n_in,
                              void* d_out, int out_size, void* d_ws, size_t ws_size,
                              hipStream_t stream) {
    const float* x    = (const float*)d_in[0];
    const int*   oh   = (const int*)d_in[1];
    const float* e0   = (const float*)d_in[2];
    const float* e1   = (const float*)d_in[3];
    const float* e2   = (const float*)d_in[4];
    const float* e3   = (const float*)d_in[5];
    const float* Wih1 = (const float*)d_in[6];
    const float* Whh1 = (const float*)d_in[7];
    const float* bih1 = (const float*)d_in[8];
    const float* bhh1 = (const float*)d_in[9];
    const float* Wih2 = (const float*)d_in[10];
    const float* Whh2 = (const float*)d_in[11];
    const float* bih2 = (const float*)d_in[12];
    const float* bhh2 = (const float*)d_in[13];
    const float* Wfc  = (const float*)d_in[14];
    const float* bfc  = (const float*)d_in[15];

    float* out    = (float*)d_out;
    float* origin = out;                                // output 0: (B,S,F)
    float* out2   = out + (size_t)BATCH * SEQ * FDIM;   // output 1: (B,S,F)

    gru_fused<<<BATCH, 128, 0, stream>>>(x, oh, e0, e1, e2, e3,
                                         Wih1, Whh1, bih1, bhh1,
                                         Wih2, Whh2, bih2, bhh2,
                                         Wfc, bfc, origin, out2);
}